// Round 7
// baseline (275.789 us; speedup 1.0000x reference)
//
#include <hip/hip_runtime.h>
#include <hip/hip_bf16.h>

// GAT attention scores:
//   e[edge,h] = aa[h,:F]·x[row] + aa[h,F:]·x[col]   (separable projections)
//   a = segment_softmax(leakyrelu(e), by row)       (shift-invariance: no max pass)
//
// R6: range_sum was occupancy-latency-bound (1568 waves, VALUBusy 3.6%).
// RNODES 512->256, SC=4, block=512 -> 784 blocks x 8 waves = 6272 waves,
// 3 blocks/CU balance. s1 gathered from global (R5's LDS preload caused
// 622k bank conflicts: (d*8)%32 spans 4 banks only). comb[] interleaves
// s1+reciprocal per node (one 64B line for both r-side gathers in edge_out).
// Nontemporal stores for the 51 MB output (via ext_vector_type — HIP float4
// class type is rejected by the builtin).
//
// ws (floats): s2[400k] comb[800k] partial[4*400k] binned[NE+1024 u32]
//              counts[78.4k] block_base[78.4k] rstart[197] rend[196] ~= 18.3 MB

constexpr int NN = 50000;
constexpr int NE = 1600000;
constexpr int F  = 32;
constexpr int H  = 8;
constexpr float ALPHA = 0.2f;
constexpr float EPS   = 1e-12f;

constexpr int RSH     = 8;
constexpr int RNODES  = 1 << RSH;                   // 256 nodes/range -> 8 KB acc
constexpr int NR      = (NN + RNODES - 1) / RNODES; // 196 ranges
constexpr int NB      = 400;                        // blocks in bin passes
constexpr int CHUNK   = NE / NB;                    // 4000 edges/block
constexpr int SC      = 4;                          // stripes in range_sum

typedef float v4f __attribute__((ext_vector_type(4)));

// comb[n]: floats [n*16+0..7] = s1 (r-side projection), [n*16+8..15] = 1/(sum+eps)

__global__ __launch_bounds__(256) void node_proj_kernel(
    const float* __restrict__ x, const float* __restrict__ aa,
    float* __restrict__ comb, float* __restrict__ s2)
{
    __shared__ float aal[H * 2 * F];
    for (int i = threadIdx.x; i < H * 2 * F; i += 256) aal[i] = aa[i];
    __syncthreads();

    int n = blockIdx.x * 256 + threadIdx.x;
    if (n >= NN) return;

    const float4* xp = reinterpret_cast<const float4*>(x + (size_t)n * F);
    float4 xv[F / 4];
#pragma unroll
    for (int i = 0; i < F / 4; ++i) xv[i] = xp[i];

    float o1[H], o2[H];
#pragma unroll
    for (int h = 0; h < H; ++h) {
        const float* a1 = &aal[h * 2 * F];
        const float* a2 = a1 + F;
        float acc1 = 0.f, acc2 = 0.f;
#pragma unroll
        for (int i = 0; i < F / 4; ++i) {
            acc1 = fmaf(a1[4*i+0], xv[i].x, acc1);
            acc1 = fmaf(a1[4*i+1], xv[i].y, acc1);
            acc1 = fmaf(a1[4*i+2], xv[i].z, acc1);
            acc1 = fmaf(a1[4*i+3], xv[i].w, acc1);
            acc2 = fmaf(a2[4*i+0], xv[i].x, acc2);
            acc2 = fmaf(a2[4*i+1], xv[i].y, acc2);
            acc2 = fmaf(a2[4*i+2], xv[i].z, acc2);
            acc2 = fmaf(a2[4*i+3], xv[i].w, acc2);
        }
        o1[h] = acc1; o2[h] = acc2;
    }

    float4* pc = reinterpret_cast<float4*>(comb + (size_t)n * 16);
    float4* p2 = reinterpret_cast<float4*>(s2 + (size_t)n * H);
    pc[0] = make_float4(o1[0], o1[1], o1[2], o1[3]);
    pc[1] = make_float4(o1[4], o1[5], o1[6], o1[7]);
    p2[0] = make_float4(o2[0], o2[1], o2[2], o2[3]);
    p2[1] = make_float4(o2[4], o2[5], o2[6], o2[7]);
}

__global__ __launch_bounds__(256) void bin_count_kernel(
    const int* __restrict__ row, int* __restrict__ counts)
{
    __shared__ int cnt[NR];
    for (int i = threadIdx.x; i < NR; i += 256) cnt[i] = 0;
    __syncthreads();
    const int base = blockIdx.x * CHUNK;
    for (int i = threadIdx.x; i < CHUNK; i += 256)
        atomicAdd(&cnt[row[base + i] >> RSH], 1);
    __syncthreads();
    for (int i = threadIdx.x; i < NR; i += 256)
        counts[i * NB + blockIdx.x] = cnt[i];
}

// one block: range starts padded to 4-entry alignment + per-(range,block) bases
__global__ __launch_bounds__(256) void scan_kernel(
    const int* __restrict__ counts, int* __restrict__ block_base,
    int* __restrict__ rstart, int* __restrict__ rend)
{
    __shared__ int rs[NR + 1];
    __shared__ int tot[NR];
    const int t = threadIdx.x;
    if (t < NR) {
        const int4* c4 = reinterpret_cast<const int4*>(counts + t * NB);
        int s = 0;
        for (int b = 0; b < NB / 4; ++b) {
            int4 v = c4[b];
            s += v.x + v.y + v.z + v.w;
        }
        tot[t] = s;
    }
    __syncthreads();
    if (t == 0) {
        int run = 0;
        for (int r = 0; r < NR; ++r) {
            run = (run + 3) & ~3;          // 16B-align each range's bin
            rs[r] = run;
            run += tot[r];
        }
        rs[NR] = (run + 3) & ~3;
    }
    __syncthreads();
    if (t < NR) {
        const int4* c4 = reinterpret_cast<const int4*>(counts + t * NB);
        int4* b4 = reinterpret_cast<int4*>(block_base + t * NB);
        int run = rs[t];
        for (int b = 0; b < NB / 4; ++b) {
            int4 v = c4[b];
            int4 o;
            o.x = run; run += v.x;
            o.y = run; run += v.y;
            o.z = run; run += v.z;
            o.w = run; run += v.w;
            b4[b] = o;
        }
        rend[t] = rs[t] + tot[t];
    }
    if (t <= NR) rstart[t] = rs[t];
}

__global__ __launch_bounds__(256) void bin_scatter_kernel(
    const int* __restrict__ row, const int* __restrict__ col,
    const int* __restrict__ block_base, const int* __restrict__ rstart,
    const int* __restrict__ rend, unsigned* __restrict__ binned)
{
    // block 0 fills alignment pads with sentinels (ws is 0xAA-poisoned!)
    // pad regions are disjoint from all scatter cursors -> race-free
    if (blockIdx.x == 0) {
        for (int r = threadIdx.x; r < NR; r += 256) {
            int p0 = rend[r], p1 = rstart[r + 1];
            for (int p = p0; p < p1; ++p) binned[p] = 0xFFFFFFFFu;
        }
    }
    __shared__ int cur[NR];
    for (int i = threadIdx.x; i < NR; i += 256)
        cur[i] = block_base[i * NB + blockIdx.x];
    __syncthreads();
    const int base = blockIdx.x * CHUNK;
    for (int i = threadIdx.x; i < CHUNK; i += 256) {
        int r = row[base + i], c = col[base + i];
        int pos = atomicAdd(&cur[r >> RSH], 1);
        binned[pos] = ((unsigned)r << 16) | (unsigned)c;   // both < 65536
    }
}

// grid (NR, SC), 512 thr: dense per-range LDS segment sum, uint4 ILP-4
__global__ __launch_bounds__(512) void range_sum_kernel(
    const unsigned* __restrict__ binned, const int* __restrict__ rstart,
    const float* __restrict__ comb, const float* __restrict__ s2,
    float* __restrict__ partial)
{
    __shared__ float acc[RNODES * H];   // 8 KB
    for (int i = threadIdx.x; i < RNODES * H; i += 512) acc[i] = 0.f;
    __syncthreads();

    const int rx = blockIdx.x;
    const int rbase = rx << RSH;
    const int beg4 = rstart[rx] >> 2, end4 = rstart[rx + 1] >> 2;  // aligned
    const uint4* b4 = reinterpret_cast<const uint4*>(binned);

    for (int i = beg4 + blockIdx.y * 512 + threadIdx.x; i < end4; i += SC * 512) {
        uint4 q = b4[i];
        unsigned qq[4] = {q.x, q.y, q.z, q.w};
        unsigned dd[4]; bool ok[4];
        float va[4][H];
#pragma unroll
        for (int k = 0; k < 4; ++k) {                 // gather phase: 8 chains
            unsigned v = qq[k];
            unsigned r = v >> 16;
            unsigned d = r - (unsigned)rbase;
            ok[k] = d < (unsigned)RNODES;             // sentinel/poison rejected
            dd[k] = d;
            unsigned rcl = ok[k] ? r : 0u;
            unsigned c   = ok[k] ? (v & 0xFFFFu) : 0u;
            const float4* p1 = reinterpret_cast<const float4*>(comb + (size_t)rcl * 16);
            const float4* p2 = reinterpret_cast<const float4*>(s2 + (size_t)c * H);
            float4 a0 = p1[0], a1 = p1[1];
            float4 b0 = p2[0], b1 = p2[1];
            va[k][0] = a0.x + b0.x; va[k][1] = a0.y + b0.y;
            va[k][2] = a0.z + b0.z; va[k][3] = a0.w + b0.w;
            va[k][4] = a1.x + b1.x; va[k][5] = a1.y + b1.y;
            va[k][6] = a1.z + b1.z; va[k][7] = a1.w + b1.w;
        }
#pragma unroll
        for (int k = 0; k < 4; ++k) {                 // compute + LDS-atomic phase
            if (!ok[k]) continue;
            unsigned d = dd[k];
            float* ap = &acc[d << 3];
#pragma unroll
            for (int h = 0; h < H; ++h) {
                float t = va[k][h];
                t = fmaxf(t, ALPHA * t);
                atomicAdd(ap + ((h + d) & 7), __expf(t));   // swizzled banks
            }
        }
    }
    __syncthreads();

    const int cnt = min(RNODES, NN - rbase);
    float* outp = partial + ((size_t)blockIdx.y * NN + rbase) * H;
    for (int j = threadIdx.x; j < cnt * H; j += 512) {
        int d = j >> 3, h = j & 7;
        outp[j] = acc[(d << 3) + ((h + d) & 7)];       // unswizzle
    }
}

// fold stripes, store reciprocal into comb[n*16+8..15]
__global__ __launch_bounds__(256) void reduce4_kernel(
    const float* __restrict__ partial, float* __restrict__ comb)
{
    int i = blockIdx.x * 256 + threadIdx.x;   // over NN*H/4 float4s
    if (i >= NN * H / 4) return;
    const float4* p4 = reinterpret_cast<const float4*>(partial);
    float4 acc = p4[i];
#pragma unroll
    for (int s = 1; s < SC; ++s) {
        float4 t = p4[(size_t)s * (NN * H / 4) + i];
        acc.x += t.x; acc.y += t.y; acc.z += t.z; acc.w += t.w;
    }
    acc.x = 1.f / (acc.x + EPS); acc.y = 1.f / (acc.y + EPS);
    acc.z = 1.f / (acc.z + EPS); acc.w = 1.f / (acc.w + EPS);
    int n = i >> 1, j = i & 1;
    reinterpret_cast<float4*>(comb)[n * 4 + 2 + j] = acc;
}

// 4 edges/thread; r-side reads hit one 64B comb line; nontemporal out stores
__global__ __launch_bounds__(256) void edge_out_kernel(
    const int* __restrict__ row, const int* __restrict__ col,
    const float* __restrict__ comb, const float* __restrict__ s2,
    float* __restrict__ out)
{
    int e0 = (blockIdx.x * 256 + threadIdx.x) * 4;
    if (e0 >= NE) return;
    int4 r4 = *reinterpret_cast<const int4*>(row + e0);
    int4 c4 = *reinterpret_cast<const int4*>(col + e0);
    int rr[4] = {r4.x, r4.y, r4.z, r4.w};
    int cc[4] = {c4.x, c4.y, c4.z, c4.w};

    float res[4][H];
#pragma unroll
    for (int k = 0; k < 4; ++k) {
        const float4* pc = reinterpret_cast<const float4*>(comb + (size_t)rr[k] * 16);
        const float4* p2 = reinterpret_cast<const float4*>(s2 + (size_t)cc[k] * H);
        float4 a0 = pc[0], a1 = pc[1];
        float4 d0 = pc[2], d1 = pc[3];
        float4 b0 = p2[0], b1 = p2[1];
        float vv[H]  = {a0.x + b0.x, a0.y + b0.y, a0.z + b0.z, a0.w + b0.w,
                        a1.x + b1.x, a1.y + b1.y, a1.z + b1.z, a1.w + b1.w};
        float rc[H]  = {d0.x, d0.y, d0.z, d0.w, d1.x, d1.y, d1.z, d1.w};
#pragma unroll
        for (int h = 0; h < H; ++h) {
            float t = vv[h];
            t = fmaxf(t, ALPHA * t);
            res[k][h] = __expf(t) * rc[h];   // exp identical to sum pass
        }
    }
#pragma unroll
    for (int h = 0; h < H; ++h) {
        v4f v = {res[0][h], res[1][h], res[2][h], res[3][h]};
        __builtin_nontemporal_store(v,
            reinterpret_cast<v4f*>(out + (size_t)h * NE + e0));
    }
}

extern "C" void kernel_launch(void* const* d_in, const int* in_sizes, int n_in,
                              void* d_out, int out_size, void* d_ws, size_t ws_size,
                              hipStream_t stream) {
    const float* x   = (const float*)d_in[0];
    const float* aa  = (const float*)d_in[1];
    const int*   row = (const int*)d_in[2];
    const int*   col = (const int*)d_in[3];
    float* out = (float*)d_out;

    float* s2      = (float*)d_ws;
    float* comb    = s2 + (size_t)NN * H;                // NN*16
    float* partial = comb + (size_t)NN * 16;             // SC * NN * H
    unsigned* binned = (unsigned*)(partial + (size_t)SC * NN * H);  // NE+1024
    int* counts     = (int*)(binned + NE + 1024);        // NR*NB
    int* block_base = counts + NR * NB;                  // NR*NB
    int* rstart     = block_base + NR * NB;              // NR+1
    int* rend       = rstart + NR + 1;                   // NR

    node_proj_kernel<<<(NN + 255) / 256, 256, 0, stream>>>(x, aa, comb, s2);
    bin_count_kernel<<<NB, 256, 0, stream>>>(row, counts);
    scan_kernel<<<1, 256, 0, stream>>>(counts, block_base, rstart, rend);
    bin_scatter_kernel<<<NB, 256, 0, stream>>>(row, col, block_base, rstart, rend, binned);
    range_sum_kernel<<<dim3(NR, SC), 512, 0, stream>>>(binned, rstart, comb, s2, partial);
    reduce4_kernel<<<(NN * H / 4 + 255) / 256, 256, 0, stream>>>(partial, comb);
    edge_out_kernel<<<(NE / 4 + 255) / 256, 256, 0, stream>>>(row, col, comb, s2, out);
}

// Round 8
// 247.918 us; speedup vs baseline: 1.1124x; 1.1124x over previous
//
#include <hip/hip_runtime.h>
#include <hip/hip_bf16.h>

// GAT attention scores:
//   e[edge,h] = aa[h,:F]·x[row] + aa[h,F:]·x[col]   (separable projections)
//   a = segment_softmax(leakyrelu(e), by row)       (shift-invariance: no max pass)
//
// R8: R4-R7 proved the edge passes are bound by divergent-gather ADDRESS
// processing (~8 addr/cyc/CU): dur invariant to occupancy/ILP, scales with
// per-edge divergent instruction count. Fix: fp16 tables halve the count.
//   s2h[n]   = 16 B (8 halves)                -> 1 instr
//   combh[n] = 32 B [s1h 8 halves | lnrech 8 halves]
// range_sum: 2 divergent instr/edge (was 4). edge_out: 3 (was 6), and
// out = exp(leaky(t) + lnrec), lnrec = -log(sum+eps) (fp16) replaces the
// fp32 reciprocal table. Sums stay fp32 in LDS. Nontemporal stores reverted.
//
// ws: s2h 800K | combh 1.6M | partial 6.4M | binned 6.4M | sort meta ~= 15.9 MB

constexpr int NN = 50000;
constexpr int NE = 1600000;
constexpr int F  = 32;
constexpr int H  = 8;
constexpr float ALPHA = 0.2f;
constexpr float EPS   = 1e-12f;

constexpr int RSH     = 8;
constexpr int RNODES  = 1 << RSH;                   // 256 nodes/range -> 8 KB acc
constexpr int NR      = (NN + RNODES - 1) / RNODES; // 196 ranges
constexpr int NB      = 400;                        // blocks in bin passes
constexpr int CHUNK   = NE / NB;                    // 4000 edges/block
constexpr int SC      = 4;                          // stripes in range_sum

typedef _Float16 v8h __attribute__((ext_vector_type(8)));

__global__ __launch_bounds__(256) void node_proj_kernel(
    const float* __restrict__ x, const float* __restrict__ aa,
    float* __restrict__ combh, float* __restrict__ s2h)
{
    __shared__ float aal[H * 2 * F];
    for (int i = threadIdx.x; i < H * 2 * F; i += 256) aal[i] = aa[i];
    __syncthreads();

    int n = blockIdx.x * 256 + threadIdx.x;
    if (n >= NN) return;

    const float4* xp = reinterpret_cast<const float4*>(x + (size_t)n * F);
    float4 xv[F / 4];
#pragma unroll
    for (int i = 0; i < F / 4; ++i) xv[i] = xp[i];

    float o1[H], o2[H];
#pragma unroll
    for (int h = 0; h < H; ++h) {
        const float* a1 = &aal[h * 2 * F];
        const float* a2 = a1 + F;
        float acc1 = 0.f, acc2 = 0.f;
#pragma unroll
        for (int i = 0; i < F / 4; ++i) {
            acc1 = fmaf(a1[4*i+0], xv[i].x, acc1);
            acc1 = fmaf(a1[4*i+1], xv[i].y, acc1);
            acc1 = fmaf(a1[4*i+2], xv[i].z, acc1);
            acc1 = fmaf(a1[4*i+3], xv[i].w, acc1);
            acc2 = fmaf(a2[4*i+0], xv[i].x, acc2);
            acc2 = fmaf(a2[4*i+1], xv[i].y, acc2);
            acc2 = fmaf(a2[4*i+2], xv[i].z, acc2);
            acc2 = fmaf(a2[4*i+3], xv[i].w, acc2);
        }
        o1[h] = acc1; o2[h] = acc2;
    }

    v8h s1v, s2v;
#pragma unroll
    for (int h = 0; h < H; ++h) { s1v[h] = (_Float16)o1[h]; s2v[h] = (_Float16)o2[h]; }
    reinterpret_cast<v8h*>(combh)[(size_t)n * 2] = s1v;   // lnrech slot filled later
    reinterpret_cast<v8h*>(s2h)[n] = s2v;
}

__global__ __launch_bounds__(256) void bin_count_kernel(
    const int* __restrict__ row, int* __restrict__ counts)
{
    __shared__ int cnt[NR];
    for (int i = threadIdx.x; i < NR; i += 256) cnt[i] = 0;
    __syncthreads();
    const int base = blockIdx.x * CHUNK;
    for (int i = threadIdx.x; i < CHUNK; i += 256)
        atomicAdd(&cnt[row[base + i] >> RSH], 1);
    __syncthreads();
    for (int i = threadIdx.x; i < NR; i += 256)
        counts[i * NB + blockIdx.x] = cnt[i];
}

// one block: range starts padded to 4-entry alignment + per-(range,block) bases
__global__ __launch_bounds__(256) void scan_kernel(
    const int* __restrict__ counts, int* __restrict__ block_base,
    int* __restrict__ rstart, int* __restrict__ rend)
{
    __shared__ int rs[NR + 1];
    __shared__ int tot[NR];
    const int t = threadIdx.x;
    if (t < NR) {
        const int4* c4 = reinterpret_cast<const int4*>(counts + t * NB);
        int s = 0;
        for (int b = 0; b < NB / 4; ++b) {
            int4 v = c4[b];
            s += v.x + v.y + v.z + v.w;
        }
        tot[t] = s;
    }
    __syncthreads();
    if (t == 0) {
        int run = 0;
        for (int r = 0; r < NR; ++r) {
            run = (run + 3) & ~3;          // 16B-align each range's bin
            rs[r] = run;
            run += tot[r];
        }
        rs[NR] = (run + 3) & ~3;
    }
    __syncthreads();
    if (t < NR) {
        const int4* c4 = reinterpret_cast<const int4*>(counts + t * NB);
        int4* b4 = reinterpret_cast<int4*>(block_base + t * NB);
        int run = rs[t];
        for (int b = 0; b < NB / 4; ++b) {
            int4 v = c4[b];
            int4 o;
            o.x = run; run += v.x;
            o.y = run; run += v.y;
            o.z = run; run += v.z;
            o.w = run; run += v.w;
            b4[b] = o;
        }
        rend[t] = rs[t] + tot[t];
    }
    if (t <= NR) rstart[t] = rs[t];
}

__global__ __launch_bounds__(256) void bin_scatter_kernel(
    const int* __restrict__ row, const int* __restrict__ col,
    const int* __restrict__ block_base, const int* __restrict__ rstart,
    const int* __restrict__ rend, unsigned* __restrict__ binned)
{
    // block 0 fills alignment pads with sentinels (ws is 0xAA-poisoned!)
    if (blockIdx.x == 0) {
        for (int r = threadIdx.x; r < NR; r += 256) {
            int p0 = rend[r], p1 = rstart[r + 1];
            for (int p = p0; p < p1; ++p) binned[p] = 0xFFFFFFFFu;
        }
    }
    __shared__ int cur[NR];
    for (int i = threadIdx.x; i < NR; i += 256)
        cur[i] = block_base[i * NB + blockIdx.x];
    __syncthreads();
    const int base = blockIdx.x * CHUNK;
    for (int i = threadIdx.x; i < CHUNK; i += 256) {
        int r = row[base + i], c = col[base + i];
        int pos = atomicAdd(&cur[r >> RSH], 1);
        binned[pos] = ((unsigned)r << 16) | (unsigned)c;   // both < 65536
    }
}

// grid (NR, SC), 512 thr: dense per-range LDS segment sum
// 2 divergent gather instrs per edge (s1h 16B + s2h 16B)
__global__ __launch_bounds__(512) void range_sum_kernel(
    const unsigned* __restrict__ binned, const int* __restrict__ rstart,
    const float* __restrict__ combh, const float* __restrict__ s2h,
    float* __restrict__ partial)
{
    __shared__ float acc[RNODES * H];   // 8 KB
    for (int i = threadIdx.x; i < RNODES * H; i += 512) acc[i] = 0.f;
    __syncthreads();

    const int rx = blockIdx.x;
    const int rbase = rx << RSH;
    const int beg4 = rstart[rx] >> 2, end4 = rstart[rx + 1] >> 2;  // aligned
    const uint4* b4 = reinterpret_cast<const uint4*>(binned);
    const v8h* combv = reinterpret_cast<const v8h*>(combh);
    const v8h* s2v   = reinterpret_cast<const v8h*>(s2h);

    for (int i = beg4 + blockIdx.y * 512 + threadIdx.x; i < end4; i += SC * 512) {
        uint4 q = b4[i];
        unsigned qq[4] = {q.x, q.y, q.z, q.w};
        unsigned dd[4]; bool ok[4];
        float va[4][H];
#pragma unroll
        for (int k = 0; k < 4; ++k) {                 // gather phase: 8 chains
            unsigned v = qq[k];
            unsigned r = v >> 16;
            unsigned d = r - (unsigned)rbase;
            ok[k] = d < (unsigned)RNODES;             // sentinel/poison rejected
            dd[k] = d;
            unsigned rcl = ok[k] ? r : 0u;
            unsigned c   = ok[k] ? (v & 0xFFFFu) : 0u;
            v8h a = combv[(size_t)rcl * 2];
            v8h b = s2v[c];
#pragma unroll
            for (int h = 0; h < H; ++h)
                va[k][h] = (float)a[h] + (float)b[h];
        }
#pragma unroll
        for (int k = 0; k < 4; ++k) {                 // compute + LDS-atomic phase
            if (!ok[k]) continue;
            unsigned d = dd[k];
            float* ap = &acc[d << 3];
#pragma unroll
            for (int h = 0; h < H; ++h) {
                float t = va[k][h];
                t = fmaxf(t, ALPHA * t);
                atomicAdd(ap + ((h + d) & 7), __expf(t));   // swizzled banks
            }
        }
    }
    __syncthreads();

    const int cnt = min(RNODES, NN - rbase);
    float* outp = partial + ((size_t)blockIdx.y * NN + rbase) * H;
    for (int j = threadIdx.x; j < cnt * H; j += 512) {
        int d = j >> 3, h = j & 7;
        outp[j] = acc[(d << 3) + ((h + d) & 7)];       // unswizzle
    }
}

// per-node: fold stripe partials, store lnrec = -log(sum+eps) as fp16
__global__ __launch_bounds__(256) void node_final_kernel(
    const float* __restrict__ partial, float* __restrict__ combh)
{
    int n = blockIdx.x * 256 + threadIdx.x;
    if (n >= NN) return;
    const float4* p4 = reinterpret_cast<const float4*>(partial);
    float4 lo = p4[(size_t)n * 2], hi = p4[(size_t)n * 2 + 1];
#pragma unroll
    for (int s = 1; s < SC; ++s) {
        float4 a = p4[(size_t)s * (NN * 2) + n * 2];
        float4 b = p4[(size_t)s * (NN * 2) + n * 2 + 1];
        lo.x += a.x; lo.y += a.y; lo.z += a.z; lo.w += a.w;
        hi.x += b.x; hi.y += b.y; hi.z += b.z; hi.w += b.w;
    }
    float s8[8] = {lo.x, lo.y, lo.z, lo.w, hi.x, hi.y, hi.z, hi.w};
    v8h lnh;
#pragma unroll
    for (int h = 0; h < H; ++h) lnh[h] = (_Float16)(-__logf(s8[h] + EPS));
    reinterpret_cast<v8h*>(combh)[(size_t)n * 2 + 1] = lnh;
}

// 4 edges/thread; 3 divergent gather instrs per edge; coalesced out stores
__global__ __launch_bounds__(256) void edge_out_kernel(
    const int* __restrict__ row, const int* __restrict__ col,
    const float* __restrict__ combh, const float* __restrict__ s2h,
    float* __restrict__ out)
{
    int e0 = (blockIdx.x * 256 + threadIdx.x) * 4;
    if (e0 >= NE) return;
    int4 r4 = *reinterpret_cast<const int4*>(row + e0);
    int4 c4 = *reinterpret_cast<const int4*>(col + e0);
    int rr[4] = {r4.x, r4.y, r4.z, r4.w};
    int cc[4] = {c4.x, c4.y, c4.z, c4.w};
    const v8h* combv = reinterpret_cast<const v8h*>(combh);
    const v8h* s2v   = reinterpret_cast<const v8h*>(s2h);

    float res[4][H];
#pragma unroll
    for (int k = 0; k < 4; ++k) {
        v8h a  = combv[(size_t)rr[k] * 2];
        v8h ln = combv[(size_t)rr[k] * 2 + 1];
        v8h b  = s2v[cc[k]];
#pragma unroll
        for (int h = 0; h < H; ++h) {
            float t = (float)a[h] + (float)b[h];
            t = fmaxf(t, ALPHA * t);
            res[k][h] = __expf(t + (float)ln[h]);   // == exp(leaky(t)) / (sum+eps)
        }
    }
#pragma unroll
    for (int h = 0; h < H; ++h) {
        *reinterpret_cast<float4*>(out + (size_t)h * NE + e0) =
            make_float4(res[0][h], res[1][h], res[2][h], res[3][h]);
    }
}

extern "C" void kernel_launch(void* const* d_in, const int* in_sizes, int n_in,
                              void* d_out, int out_size, void* d_ws, size_t ws_size,
                              hipStream_t stream) {
    const float* x   = (const float*)d_in[0];
    const float* aa  = (const float*)d_in[1];
    const int*   row = (const int*)d_in[2];
    const int*   col = (const int*)d_in[3];
    float* out = (float*)d_out;

    float* s2h     = (float*)d_ws;                       // NN*4 floats (fp16 x8)
    float* combh   = s2h + (size_t)NN * 4;               // NN*8 floats (fp16 x16)
    float* partial = combh + (size_t)NN * 8;             // SC * NN * H
    unsigned* binned = (unsigned*)(partial + (size_t)SC * NN * H);  // NE+1024
    int* counts     = (int*)(binned + NE + 1024);        // NR*NB
    int* block_base = counts + NR * NB;                  // NR*NB
    int* rstart     = block_base + NR * NB;              // NR+1
    int* rend       = rstart + NR + 1;                   // NR

    node_proj_kernel<<<(NN + 255) / 256, 256, 0, stream>>>(x, aa, combh, s2h);
    bin_count_kernel<<<NB, 256, 0, stream>>>(row, counts);
    scan_kernel<<<1, 256, 0, stream>>>(counts, block_base, rstart, rend);
    bin_scatter_kernel<<<NB, 256, 0, stream>>>(row, col, block_base, rstart, rend, binned);
    range_sum_kernel<<<dim3(NR, SC), 512, 0, stream>>>(binned, rstart, combh, s2h, partial);
    node_final_kernel<<<(NN + 255) / 256, 256, 0, stream>>>(partial, combh);
    edge_out_kernel<<<(NE / 4 + 255) / 256, 256, 0, stream>>>(row, col, combh, s2h, out);
}